// Round 14
// baseline (4519.036 us; speedup 1.0000x reference)
//
#include <hip/hip_runtime.h>
#include <cstdint>

#define B_  64
#define T_  1024
#define I_  256
#define H_  512

typedef _Float16 h2_t __attribute__((ext_vector_type(2)));
typedef int sv16 __attribute__((ext_vector_type(16)));
typedef _Float16 f16x8 __attribute__((ext_vector_type(8)));
typedef float f32x4 __attribute__((ext_vector_type(4)));

__device__ __forceinline__ uint32_t f2h(float f) {
  _Float16 h = (_Float16)f;                        // v_cvt_f16_f32, RNE
  return (uint32_t)__builtin_bit_cast(uint16_t, h);
}
__device__ __forceinline__ float dot2(uint32_t a, uint32_t b, float c) {
  return __builtin_amdgcn_fdot2(__builtin_bit_cast(h2_t, a),
                                __builtin_bit_cast(h2_t, b), c, false);
}
__device__ __forceinline__ float fast_tanh(float s) {
  float e = __expf(2.0f * s);
  return fmaf(-2.0f, __builtin_amdgcn_rcpf(e + 1.0f), 1.0f);
}

// select h pair P (0..63 within one h-quarter) from 4x16 SGPR vectors
template<int P>
__device__ __forceinline__ uint32_t hsel(sv16 h0, sv16 h1, sv16 h2, sv16 h3) {
  if constexpr (P < 16)      return (uint32_t)h0[P];
  else if constexpr (P < 32) return (uint32_t)h1[P - 16];
  else if constexpr (P < 48) return (uint32_t)h2[P - 32];
  else                       return (uint32_t)h3[P - 48];
}

// ---------- W_hh pack (scan weights) ----------
// [k8 (64)][j (512)][m (4)] u32; u32 m at (k8,j) = (W[k][j],W[k+1][j]), k=8*k8+2m.
__global__ void pack_whh(const float* __restrict__ W, uint32_t* __restrict__ out) {
  int idx = blockIdx.x * 256 + threadIdx.x;        // [0, 131072)
  int k8 = idx >> 11;
  int j  = (idx >> 2) & 511;
  int m  = idx & 3;
  int k  = k8 * 8 + m * 2;
  uint32_t lo = f2h(W[k * H_ + j]);
  uint32_t hi = f2h(W[(k + 1) * H_ + j]);
  out[idx] = lo | (hi << 16);
}

// ---------- W_ih pack into MFMA B-fragment order ----------
template<int K>
__global__ __launch_bounds__(512) void pack_wih(const float* __restrict__ W,
                                                uint4* __restrict__ out) {
  constexpr int KS = K / 32;
  int t = blockIdx.x * 512 + threadIdx.x;          // [0, 32*KS*64)
  int l  = t & 63;
  int ks = (t >> 6) % KS;
  int cb = t / (64 * KS);
  int c  = cb * 16 + (l & 15);
  int k0 = ks * 32 + ((l >> 4) & 3) * 8;
  uint4 u;
  u.x = f2h(W[(k0 + 0) * H_ + c]) | (f2h(W[(k0 + 1) * H_ + c]) << 16);
  u.y = f2h(W[(k0 + 2) * H_ + c]) | (f2h(W[(k0 + 3) * H_ + c]) << 16);
  u.z = f2h(W[(k0 + 4) * H_ + c]) | (f2h(W[(k0 + 5) * H_ + c]) << 16);
  u.w = f2h(W[(k0 + 6) * H_ + c]) | (f2h(W[(k0 + 7) * H_ + c]) << 16);
  out[t] = u;
}

// ---------- MFMA f16 GEMM: Y[64 rows/block] = A @ W + bias (proven R11) ----------
template<int K>
__global__ __launch_bounds__(512) void gemm_mfma(const float* A,
    const uint4* __restrict__ WT, const float* __restrict__ bias, float* Y) {
  constexpr int KS = K / 32;
  __shared__ __align__(16) char As[64 * K * 2];    // f16, swizzled
  const int tid = threadIdx.x;
  const size_t row0 = (size_t)blockIdx.x * 64;

  const float4* Ab4 = (const float4*)(A + row0 * K);
  #pragma unroll
  for (int it = 0; it < K / 32; ++it) {
    int i4 = tid + it * 512;
    int fi = i4 * 4;
    int row = fi / K;
    int kk  = fi - row * K;
    float4 v = Ab4[i4];
    uint2 u;
    u.x = f2h(v.x) | (f2h(v.y) << 16);
    u.y = f2h(v.z) | (f2h(v.w) << 16);
    int off = row * (2 * K) + ((kk * 2) ^ ((row & 7) << 4));
    *(uint2*)(As + off) = u;
  }
  __syncthreads();

  const int lane = tid & 63;
  const int wv   = tid >> 6;
  const int rw   = wv >> 1;
  const int ch   = wv & 1;

  f32x4 acc[16];
  #pragma unroll
  for (int cf = 0; cf < 16; ++cf) {
    float bz = bias[ch * 256 + cf * 16 + (lane & 15)];
    acc[cf] = (f32x4){bz, bz, bz, bz};
  }

  const int arow = rw * 16 + (lane & 15);
  const int abase = arow * (2 * K);
  const int aswz = (arow & 7) << 4;
  for (int ks = 0; ks < KS; ++ks) {
    int kbyte = ks * 64 + ((lane >> 4) & 3) * 16;
    f16x8 af = *(const f16x8*)(As + abase + (kbyte ^ aswz));
    #pragma unroll
    for (int cf = 0; cf < 16; ++cf) {
      uint4 bu = WT[(size_t)((ch * 16 + cf) * KS + ks) * 64 + lane];
      f16x8 bf = __builtin_bit_cast(f16x8, bu);
      acc[cf] = __builtin_amdgcn_mfma_f32_16x16x32_f16(af, bf, acc[cf], 0, 0, 0);
    }
  }
  __syncthreads();                                 // all A reads done before write (in-place)

  const int wrow = rw * 16 + ((lane >> 4) & 3) * 4;
  #pragma unroll
  for (int cf = 0; cf < 16; ++cf) {
    int col = ch * 256 + cf * 16 + (lane & 15);
    float* Yp = Y + (row0 + wrow) * H_ + col;
    #pragma unroll
    for (int r = 0; r < 4; ++r) Yp[r * H_] = acc[cf][r];
  }
}

// ---------- AGPR pinning: physical a<N> registers the allocator can't touch ----------
#define AWr(N, V) asm volatile("v_accvgpr_write_b32 a" #N ", %0" :: "v"(V) : "a" #N)
#define ARr(N, V) asm volatile("v_accvgpr_read_b32 %0, a" #N : "=v"(V))
#define AWS(N0,N1,N2,N3, U) AWr(N0,(U).x); AWr(N1,(U).y); AWr(N2,(U).z); AWr(N3,(U).w)
#define PLD(S, N0,N1,N2,N3) { uint4 u_ = Wp[(S) * H_ + j]; AWS(N0,N1,N2,N3, u_); }

// ---------- scan ----------
#define ROW(m, WEXPR) { uint4 w_ = (WEXPR); \
  a0 = dot2(w_.x, hsel<4*(m)+0>(h0,h1,h2,h3), a0); \
  a1 = dot2(w_.y, hsel<4*(m)+1>(h0,h1,h2,h3), a1); \
  a2 = dot2(w_.z, hsel<4*(m)+2>(h0,h1,h2,h3), a2); \
  a3 = dot2(w_.w, hsel<4*(m)+3>(h0,h1,h2,h3), a3); }

// AGPR-sourced ROW: read 4 pinned AGPRs, then 4 dot2s
#define ROWA(m, N0,N1,N2,N3) { uint4 w_; \
  ARr(N0, w_.x); ARr(N1, w_.y); ARr(N2, w_.z); ARr(N3, w_.w); \
  a0 = dot2(w_.x, hsel<4*(m)+0>(h0,h1,h2,h3), a0); \
  a1 = dot2(w_.y, hsel<4*(m)+1>(h0,h1,h2,h3), a1); \
  a2 = dot2(w_.z, hsel<4*(m)+2>(h0,h1,h2,h3), a2); \
  a3 = dot2(w_.w, hsel<4*(m)+3>(h0,h1,h2,h3), a3); }

// R10-exact: fused wait + early-clobber + sched_barrier(0) (proven 1550us)
#define BATCH_LOAD(OFF0, OFF1, OFF2, OFF3) \
  asm volatile("s_load_dwordx16 %0, %4, " OFF0 "\n\t" \
               "s_load_dwordx16 %1, %4, " OFF1 "\n\t" \
               "s_load_dwordx16 %2, %4, " OFF2 "\n\t" \
               "s_load_dwordx16 %3, %4, " OFF3 "\n\t" \
               "s_waitcnt lgkmcnt(0)" \
               : "=&s"(h0), "=&s"(h1), "=&s"(h2), "=&s"(h3) : "s"(hbase)); \
  __builtin_amdgcn_sched_barrier(0);

#define CONS16(W0)  ROW(0,W0(0))  ROW(1,W0(1))  ROW(2,W0(2))  ROW(3,W0(3)) \
                    ROW(4,W0(4))  ROW(5,W0(5))  ROW(6,W0(6))  ROW(7,W0(7)) \
                    ROW(8,W0(8))  ROW(9,W0(9))  ROW(10,W0(10)) ROW(11,W0(11)) \
                    ROW(12,W0(12)) ROW(13,W0(13)) ROW(14,W0(14)) ROW(15,W0(15))

// quarter 0: slabs 0..15 in a0..a63
#define CONSA0 \
  ROWA(0,  0,1,2,3)     ROWA(1,  4,5,6,7)     ROWA(2,  8,9,10,11)   ROWA(3,  12,13,14,15) \
  ROWA(4,  16,17,18,19) ROWA(5,  20,21,22,23) ROWA(6,  24,25,26,27) ROWA(7,  28,29,30,31) \
  ROWA(8,  32,33,34,35) ROWA(9,  36,37,38,39) ROWA(10, 40,41,42,43) ROWA(11, 44,45,46,47) \
  ROWA(12, 48,49,50,51) ROWA(13, 52,53,54,55) ROWA(14, 56,57,58,59) ROWA(15, 60,61,62,63)
// quarter 1: slabs 16..31 in a64..a127
#define CONSA1 \
  ROWA(0,  64,65,66,67)     ROWA(1,  68,69,70,71)     ROWA(2,  72,73,74,75)     ROWA(3,  76,77,78,79) \
  ROWA(4,  80,81,82,83)     ROWA(5,  84,85,86,87)     ROWA(6,  88,89,90,91)     ROWA(7,  92,93,94,95) \
  ROWA(8,  96,97,98,99)     ROWA(9,  100,101,102,103) ROWA(10, 104,105,106,107) ROWA(11, 108,109,110,111) \
  ROWA(12, 112,113,114,115) ROWA(13, 116,117,118,119) ROWA(14, 120,121,122,123) ROWA(15, 124,125,126,127)

#define WLDS(m)  WL[(m) * 512 + j]  // slabs 32..47 (LDS-resident), quarter 2
#define WSTR(m)  g[m]               // slabs 48..63 (loop-top stream), quarter 3

// Persistent scan: one WG per batch, thread j owns hidden unit j.
// h broadcast via SGPRs (global PING-PONG round-trip + s_load_dwordx16 after
// s_dcache_inv). R10 consume topology (proven best), with one change (R14):
// slabs 0..31 live in PHYSICAL AGPRs a0..a127 (v_accvgpr_write at preload,
// v_accvgpr_read in-loop). Literal registers are outside the allocator's
// reach -- no sinking (R2), no spilling (R6/R7/R8). Unified-file budget:
// <=128 VGPR + 128 AGPR = 256/wave = exactly the 2-waves/SIMD limit.
// Per-step L2 stream drops 384 KB -> 128 KB (g[16] only).
__global__ __launch_bounds__(512, 2) void rnn_scan(float* Y,
    const uint4* __restrict__ Wp, ushort* __restrict__ hb16,
    float* __restrict__ hn) {
  __shared__ uint4 WL[16 * 512];                   // 128 KB: slabs 32..47
  const int j = threadIdx.x;
  float* Yb = Y + (size_t)blockIdx.x * (T_ * H_);
  ushort* hp0 = hb16 + blockIdx.x * (2 * H_);      // ping
  ushort* hp1 = hp0 + H_;                          // pong

  // preload slabs 0..31 into AGPRs a0..a127 (4 regs per slab)
  PLD(0,  0,1,2,3)       PLD(1,  4,5,6,7)       PLD(2,  8,9,10,11)     PLD(3,  12,13,14,15)
  PLD(4,  16,17,18,19)   PLD(5,  20,21,22,23)   PLD(6,  24,25,26,27)   PLD(7,  28,29,30,31)
  PLD(8,  32,33,34,35)   PLD(9,  36,37,38,39)   PLD(10, 40,41,42,43)   PLD(11, 44,45,46,47)
  PLD(12, 48,49,50,51)   PLD(13, 52,53,54,55)   PLD(14, 56,57,58,59)   PLD(15, 60,61,62,63)
  PLD(16, 64,65,66,67)   PLD(17, 68,69,70,71)   PLD(18, 72,73,74,75)   PLD(19, 76,77,78,79)
  PLD(20, 80,81,82,83)   PLD(21, 84,85,86,87)   PLD(22, 88,89,90,91)   PLD(23, 92,93,94,95)
  PLD(24, 96,97,98,99)   PLD(25, 100,101,102,103) PLD(26, 104,105,106,107) PLD(27, 108,109,110,111)
  PLD(28, 112,113,114,115) PLD(29, 116,117,118,119) PLD(30, 120,121,122,123) PLD(31, 124,125,126,127)
  // LDS slabs 32..47
  #pragma unroll
  for (int it = 0; it < 16; ++it) WL[it * 512 + j] = Wp[(32 + it) * 512 + j];

  float xp0 = Yb[j];
  float v = fast_tanh(xp0);
  hp0[j] = (ushort)f2h(v);
  Yb[j] = v;
  const uint64_t hb0 = (uint64_t)(uintptr_t)hp0;
  const uint64_t hb1 = (uint64_t)(uintptr_t)hp1;
  asm volatile("s_waitcnt vmcnt(0) lgkmcnt(0)\n\ts_barrier\n\ts_dcache_inv" ::: "memory");

  for (int t = 1; t < T_; ++t) {
    const uint64_t hbase = (t & 1) ? hb0 : hb1;    // read h(t-1)
    ushort* hst = (t & 1) ? hp1 : hp0;             // store h(t)
    float xpt = Yb[t * H_ + j];
    uint4 g[16];                                   // streamed slabs 48..63
    #pragma unroll
    for (int m = 0; m < 16; ++m) g[m] = Wp[(48 + m) * H_ + j];
    float a0 = 0.f, a1 = 0.f, a2 = 0.f, a3 = 0.f;
    sv16 h0, h1, h2, h3;

    BATCH_LOAD("0x0", "0x40", "0x80", "0xc0")      // h quarter 0
    CONSA0
    BATCH_LOAD("0x100", "0x140", "0x180", "0x1c0") // h quarter 1
    CONSA1
    BATCH_LOAD("0x200", "0x240", "0x280", "0x2c0") // h quarter 2
    CONS16(WLDS)
    BATCH_LOAD("0x300", "0x340", "0x380", "0x3c0") // h quarter 3
    CONS16(WSTR)

    float s = xpt + ((a0 + a1) + (a2 + a3));
    v = fast_tanh(s);
    hst[j] = (ushort)f2h(v);
    asm volatile("s_waitcnt vmcnt(0)\n\ts_barrier\n\ts_dcache_inv" ::: "memory");
    Yb[t * H_ + j] = v;                            // drains under next step
  }
  hn[blockIdx.x * H_ + j] = v;
}

extern "C" void kernel_launch(void* const* d_in, const int* in_sizes, int n_in,
                              void* d_out, int out_size, void* d_ws, size_t ws_size,
                              hipStream_t stream) {
  const float* x     = (const float*)d_in[0];
  const float* W_ih0 = (const float*)d_in[1];
  const float* W_hh0 = (const float*)d_in[2];
  const float* b0    = (const float*)d_in[3];
  const float* W_ih1 = (const float*)d_in[4];
  const float* W_hh1 = (const float*)d_in[5];
  const float* b1    = (const float*)d_in[6];

  float* Y  = (float*)d_out;                        // [64][1024][512]
  float* hn = Y + (size_t)B_ * T_ * H_;             // [2][64][512]
  uint32_t* Wp = (uint32_t*)d_ws;                   // [0,512K): f16 W_hh (per layer)
  ushort* hbuf = (ushort*)((char*)d_ws + 512 * 1024);   // [512K,640K): ping-pong h
  uint4* WT  = (uint4*)((char*)d_ws + 640 * 1024);      // [640K,1152K): W_ih B-frags

  // layer 0
  pack_whh<<<512, 256, 0, stream>>>(W_hh0, Wp);
  pack_wih<I_><<<32, 512, 0, stream>>>(W_ih0, WT);
  gemm_mfma<I_><<<1024, 512, 0, stream>>>(x, WT, b0, Y);
  rnn_scan<<<B_, H_, 0, stream>>>(Y, (const uint4*)Wp, hbuf, hn);
  // layer 1
  pack_whh<<<512, 256, 0, stream>>>(W_hh1, Wp);
  pack_wih<H_><<<64, 512, 0, stream>>>(W_ih1, WT);
  gemm_mfma<H_><<<1024, 512, 0, stream>>>(Y, WT, b1, Y);
  rnn_scan<<<B_, H_, 0, stream>>>(Y, (const uint4*)Wp, hbuf, hn + B_ * H_);
}

// Round 15
// 3361.245 us; speedup vs baseline: 1.3445x; 1.3445x over previous
//
#include <hip/hip_runtime.h>
#include <cstdint>

#define B_  64
#define T_  1024
#define I_  256
#define H_  512

typedef _Float16 h2_t __attribute__((ext_vector_type(2)));
typedef int sv16 __attribute__((ext_vector_type(16)));
typedef _Float16 f16x8 __attribute__((ext_vector_type(8)));
typedef float f32x4 __attribute__((ext_vector_type(4)));

__device__ __forceinline__ uint32_t f2h(float f) {
  _Float16 h = (_Float16)f;                        // v_cvt_f16_f32, RNE
  return (uint32_t)__builtin_bit_cast(uint16_t, h);
}
__device__ __forceinline__ float dot2(uint32_t a, uint32_t b, float c) {
  return __builtin_amdgcn_fdot2(__builtin_bit_cast(h2_t, a),
                                __builtin_bit_cast(h2_t, b), c, false);
}
__device__ __forceinline__ float fast_tanh(float s) {
  float e = __expf(2.0f * s);
  return fmaf(-2.0f, __builtin_amdgcn_rcpf(e + 1.0f), 1.0f);
}

// select h pair P (0..63 within one h-quarter) from 4x16 SGPR vectors
template<int P>
__device__ __forceinline__ uint32_t hsel(sv16 h0, sv16 h1, sv16 h2, sv16 h3) {
  if constexpr (P < 16)      return (uint32_t)h0[P];
  else if constexpr (P < 32) return (uint32_t)h1[P - 16];
  else if constexpr (P < 48) return (uint32_t)h2[P - 32];
  else                       return (uint32_t)h3[P - 48];
}

// ---------- W_hh pack (scan weights) ----------
// [k8 (64)][j (512)][m (4)] u32; u32 m at (k8,j) = (W[k][j],W[k+1][j]), k=8*k8+2m.
__global__ void pack_whh(const float* __restrict__ W, uint32_t* __restrict__ out) {
  int idx = blockIdx.x * 256 + threadIdx.x;        // [0, 131072)
  int k8 = idx >> 11;
  int j  = (idx >> 2) & 511;
  int m  = idx & 3;
  int k  = k8 * 8 + m * 2;
  uint32_t lo = f2h(W[k * H_ + j]);
  uint32_t hi = f2h(W[(k + 1) * H_ + j]);
  out[idx] = lo | (hi << 16);
}

// ---------- W_ih pack into MFMA B-fragment order ----------
template<int K>
__global__ __launch_bounds__(512) void pack_wih(const float* __restrict__ W,
                                                uint4* __restrict__ out) {
  constexpr int KS = K / 32;
  int t = blockIdx.x * 512 + threadIdx.x;          // [0, 32*KS*64)
  int l  = t & 63;
  int ks = (t >> 6) % KS;
  int cb = t / (64 * KS);
  int c  = cb * 16 + (l & 15);
  int k0 = ks * 32 + ((l >> 4) & 3) * 8;
  uint4 u;
  u.x = f2h(W[(k0 + 0) * H_ + c]) | (f2h(W[(k0 + 1) * H_ + c]) << 16);
  u.y = f2h(W[(k0 + 2) * H_ + c]) | (f2h(W[(k0 + 3) * H_ + c]) << 16);
  u.z = f2h(W[(k0 + 4) * H_ + c]) | (f2h(W[(k0 + 5) * H_ + c]) << 16);
  u.w = f2h(W[(k0 + 6) * H_ + c]) | (f2h(W[(k0 + 7) * H_ + c]) << 16);
  out[t] = u;
}

// ---------- MFMA f16 GEMM: Y[64 rows/block] = A @ W + bias (proven R11) ----------
template<int K>
__global__ __launch_bounds__(512) void gemm_mfma(const float* A,
    const uint4* __restrict__ WT, const float* __restrict__ bias, float* Y) {
  constexpr int KS = K / 32;
  __shared__ __align__(16) char As[64 * K * 2];    // f16, swizzled
  const int tid = threadIdx.x;
  const size_t row0 = (size_t)blockIdx.x * 64;

  const float4* Ab4 = (const float4*)(A + row0 * K);
  #pragma unroll
  for (int it = 0; it < K / 32; ++it) {
    int i4 = tid + it * 512;
    int fi = i4 * 4;
    int row = fi / K;
    int kk  = fi - row * K;
    float4 v = Ab4[i4];
    uint2 u;
    u.x = f2h(v.x) | (f2h(v.y) << 16);
    u.y = f2h(v.z) | (f2h(v.w) << 16);
    int off = row * (2 * K) + ((kk * 2) ^ ((row & 7) << 4));
    *(uint2*)(As + off) = u;
  }
  __syncthreads();

  const int lane = tid & 63;
  const int wv   = tid >> 6;
  const int rw   = wv >> 1;
  const int ch   = wv & 1;

  f32x4 acc[16];
  #pragma unroll
  for (int cf = 0; cf < 16; ++cf) {
    float bz = bias[ch * 256 + cf * 16 + (lane & 15)];
    acc[cf] = (f32x4){bz, bz, bz, bz};
  }

  const int arow = rw * 16 + (lane & 15);
  const int abase = arow * (2 * K);
  const int aswz = (arow & 7) << 4;
  for (int ks = 0; ks < KS; ++ks) {
    int kbyte = ks * 64 + ((lane >> 4) & 3) * 16;
    f16x8 af = *(const f16x8*)(As + abase + (kbyte ^ aswz));
    #pragma unroll
    for (int cf = 0; cf < 16; ++cf) {
      uint4 bu = WT[(size_t)((ch * 16 + cf) * KS + ks) * 64 + lane];
      f16x8 bf = __builtin_bit_cast(f16x8, bu);
      acc[cf] = __builtin_amdgcn_mfma_f32_16x16x32_f16(af, bf, acc[cf], 0, 0, 0);
    }
  }
  __syncthreads();                                 // all A reads done before write (in-place)

  const int wrow = rw * 16 + ((lane >> 4) & 3) * 4;
  #pragma unroll
  for (int cf = 0; cf < 16; ++cf) {
    int col = ch * 256 + cf * 16 + (lane & 15);
    float* Yp = Y + (row0 + wrow) * H_ + col;
    #pragma unroll
    for (int r = 0; r < 4; ++r) Yp[r * H_] = acc[cf][r];
  }
}

// ---------- scan: R10 body (proven best), LDS share grown 16 -> 18 slabs ----------
#define ROW(m, WEXPR) { uint4 w_ = (WEXPR); \
  a0 = dot2(w_.x, hsel<4*(m)+0>(h0,h1,h2,h3), a0); \
  a1 = dot2(w_.y, hsel<4*(m)+1>(h0,h1,h2,h3), a1); \
  a2 = dot2(w_.z, hsel<4*(m)+2>(h0,h1,h2,h3), a2); \
  a3 = dot2(w_.w, hsel<4*(m)+3>(h0,h1,h2,h3), a3); }

// R10-exact: fused wait + early-clobber + sched_barrier(0) (proven 1550us)
#define BATCH_LOAD(OFF0, OFF1, OFF2, OFF3) \
  asm volatile("s_load_dwordx16 %0, %4, " OFF0 "\n\t" \
               "s_load_dwordx16 %1, %4, " OFF1 "\n\t" \
               "s_load_dwordx16 %2, %4, " OFF2 "\n\t" \
               "s_load_dwordx16 %3, %4, " OFF3 "\n\t" \
               "s_waitcnt lgkmcnt(0)" \
               : "=&s"(h0), "=&s"(h1), "=&s"(h2), "=&s"(h3) : "s"(hbase)); \
  __builtin_amdgcn_sched_barrier(0);

#define CONS16(W0)  ROW(0,W0(0))  ROW(1,W0(1))  ROW(2,W0(2))  ROW(3,W0(3)) \
                    ROW(4,W0(4))  ROW(5,W0(5))  ROW(6,W0(6))  ROW(7,W0(7)) \
                    ROW(8,W0(8))  ROW(9,W0(9))  ROW(10,W0(10)) ROW(11,W0(11)) \
                    ROW(12,W0(12)) ROW(13,W0(13)) ROW(14,W0(14)) ROW(15,W0(15))

// Slab map (R15): wrv = slabs 0..29 (compiler-streamed), WL = slabs 30..47
// (18 slabs, 144KB LDS), g = slabs 48..63 (explicit loop-top stream).
#define WREG0(m) wrv[m]                         // q0: slabs  0..15
#define WQ1(m)   ((m) < 14 ? wrv[16 + (m)] : WL[((m) - 14) * 512 + j])  // q1: 16..29 wrv, 30..31 WL
#define WLDS2(m) WL[(2 + (m)) * 512 + j]        // q2: slabs 32..47 = WL rows 2..17
#define WSTR(m)  g[m]                           // q3: slabs 48..63

// Persistent scan: one WG per batch, thread j owns hidden unit j.
// h broadcast via SGPRs (global PING-PONG round-trip + s_load_dwordx16 after
// s_dcache_inv; ping-pong kills the R4 WAR race). R10 consume topology --
// five schedule/residency variants (R12 reorder, R13 rotate, R14 AGPR pin,
// R6/R7 VGPR pin) all regressed; the compiler-streamed form is the optimum.
// R15: LDS W share 16->18 slabs, per-step L2 stream 384->368 KB.
__global__ __launch_bounds__(512, 2) void rnn_scan(float* Y,
    const uint4* __restrict__ Wp, ushort* __restrict__ hb16,
    float* __restrict__ hn) {
  __shared__ uint4 WL[18 * 512];                   // 144 KB: slabs 30..47
  const int j = threadIdx.x;
  float* Yb = Y + (size_t)blockIdx.x * (T_ * H_);
  ushort* hp0 = hb16 + blockIdx.x * (2 * H_);      // ping
  ushort* hp1 = hp0 + H_;                          // pong

  uint4 wrv[30];                                   // slabs 0..29 (compiler-managed)
  #pragma unroll
  for (int m = 0; m < 30; ++m) wrv[m] = Wp[m * H_ + j];
  #pragma unroll
  for (int it = 0; it < 18; ++it) WL[it * 512 + j] = Wp[(30 + it) * 512 + j];

  float xp0 = Yb[j];
  float v = fast_tanh(xp0);
  hp0[j] = (ushort)f2h(v);
  Yb[j] = v;
  const uint64_t hb0 = (uint64_t)(uintptr_t)hp0;
  const uint64_t hb1 = (uint64_t)(uintptr_t)hp1;
  asm volatile("s_waitcnt vmcnt(0) lgkmcnt(0)\n\ts_barrier\n\ts_dcache_inv" ::: "memory");

  for (int t = 1; t < T_; ++t) {
    const uint64_t hbase = (t & 1) ? hb0 : hb1;    // read h(t-1)
    ushort* hst = (t & 1) ? hp1 : hp0;             // store h(t)
    float xpt = Yb[t * H_ + j];
    uint4 g[16];                                   // streamed slabs 48..63
    #pragma unroll
    for (int m = 0; m < 16; ++m) g[m] = Wp[(48 + m) * H_ + j];
    float a0 = 0.f, a1 = 0.f, a2 = 0.f, a3 = 0.f;
    sv16 h0, h1, h2, h3;

    BATCH_LOAD("0x0", "0x40", "0x80", "0xc0")      // h quarter 0
    CONS16(WREG0)
    BATCH_LOAD("0x100", "0x140", "0x180", "0x1c0") // h quarter 1
    CONS16(WQ1)
    BATCH_LOAD("0x200", "0x240", "0x280", "0x2c0") // h quarter 2
    CONS16(WLDS2)
    BATCH_LOAD("0x300", "0x340", "0x380", "0x3c0") // h quarter 3
    CONS16(WSTR)

    float s = xpt + ((a0 + a1) + (a2 + a3));
    v = fast_tanh(s);
    hst[j] = (ushort)f2h(v);
    asm volatile("s_waitcnt vmcnt(0)\n\ts_barrier\n\ts_dcache_inv" ::: "memory");
    Yb[t * H_ + j] = v;                            // drains under next step
  }
  hn[blockIdx.x * H_ + j] = v;
}

extern "C" void kernel_launch(void* const* d_in, const int* in_sizes, int n_in,
                              void* d_out, int out_size, void* d_ws, size_t ws_size,
                              hipStream_t stream) {
  const float* x     = (const float*)d_in[0];
  const float* W_ih0 = (const float*)d_in[1];
  const float* W_hh0 = (const float*)d_in[2];
  const float* b0    = (const float*)d_in[3];
  const float* W_ih1 = (const float*)d_in[4];
  const float* W_hh1 = (const float*)d_in[5];
  const float* b1    = (const float*)d_in[6];

  float* Y  = (float*)d_out;                        // [64][1024][512]
  float* hn = Y + (size_t)B_ * T_ * H_;             // [2][64][512]
  uint32_t* Wp = (uint32_t*)d_ws;                   // [0,512K): f16 W_hh (per layer)
  ushort* hbuf = (ushort*)((char*)d_ws + 512 * 1024);   // [512K,640K): ping-pong h
  uint4* WT  = (uint4*)((char*)d_ws + 640 * 1024);      // [640K,1152K): W_ih B-frags

  // layer 0
  pack_whh<<<512, 256, 0, stream>>>(W_hh0, Wp);
  pack_wih<I_><<<32, 512, 0, stream>>>(W_ih0, WT);
  gemm_mfma<I_><<<1024, 512, 0, stream>>>(x, WT, b0, Y);
  rnn_scan<<<B_, H_, 0, stream>>>(Y, (const uint4*)Wp, hbuf, hn);
  // layer 1
  pack_whh<<<512, 256, 0, stream>>>(W_hh1, Wp);
  pack_wih<H_><<<64, 512, 0, stream>>>(W_ih1, WT);
  gemm_mfma<H_><<<1024, 512, 0, stream>>>(Y, WT, b1, Y);
  rnn_scan<<<B_, H_, 0, stream>>>(Y, (const uint4*)Wp, hbuf, hn + B_ * H_);
}